// Round 6
// baseline (191.778 us; speedup 1.0000x reference)
//
#include <hip/hip_runtime.h>
#include <hip/hip_bf16.h>

// ---------------------------------------------------------------------------
// CrossFormerBlock on MI355X (gfx950)
// B=1 D=16 H=32 W=32 T=4 C=128, G=4, NH=8, HD=16, NW=256 windows, N=256 tok/win
// R6: GEMM epilogue VALU fix — per-fragment index hoisting (dst = base +
// r*stride), erff -> sigmoid-form tanh-GELU, compile-time K. Rest unchanged.
// ---------------------------------------------------------------------------

typedef __attribute__((ext_vector_type(8))) short  s16x8;
typedef __attribute__((ext_vector_type(4))) short  s16x4;
typedef __attribute__((ext_vector_type(4))) float  f32x4;

#define CC    128
#define NWIN  256
#define NTOK  256
#define TOKS  65536            // total tokens = NWIN*NTOK = D*H*W*T
#define SCALE 0.25f
#define LNEPS 1e-5f

__device__ __forceinline__ float b2f(short s) {
  union { unsigned u; float f; } c; c.u = ((unsigned)(unsigned short)s) << 16; return c.f;
}
__device__ __forceinline__ short f2b(float f) {
  __hip_bfloat16 h = __float2bfloat16(f);
  return *reinterpret_cast<short*>(&h);
}
__device__ __forceinline__ float fast_gelu(float x) {
  // 0.5x(1+tanh(0.79788456(x+0.044715x^3))) == x * sigmoid(1.59577(x+0.044715x^3))
  float u = 1.595769122f * x * fmaf(0.044715f, x*x, 1.0f);
  return x / (1.0f + __expf(-u));
}

__device__ __forceinline__ f32x4 mfma16x16x16_bf16(s16x4 a, s16x4 b, f32x4 c) {
#if __has_builtin(__builtin_amdgcn_mfma_f32_16x16x16_bf16)
  return __builtin_amdgcn_mfma_f32_16x16x16_bf16(a, b, c, 0, 0, 0);
#elif __has_builtin(__builtin_amdgcn_mfma_f32_16x16x16bf16_1k)
  return __builtin_amdgcn_mfma_f32_16x16x16bf16_1k(a, b, c, 0, 0, 0);
#else
  f32x4 d;
  asm("v_mfma_f32_16x16x16_bf16 %0, %1, %2, %3" : "=v"(d) : "v"(a), "v"(b), "v"(c));
  return d;
#endif
}

// ---------------------------------------------------------------------------
// Kernel 0: weight prep — fp32->bf16 copies of GEMM weights + conv_w transpose
// ---------------------------------------------------------------------------
__global__ void prep_kernel(const float* __restrict__ qkv_w, const float* __restrict__ proj_w,
                            const float* __restrict__ fc1_w, const float* __restrict__ fc2_w,
                            const float* __restrict__ conv_w,
                            __hip_bfloat16* wq, __hip_bfloat16* wp,
                            __hip_bfloat16* w1, __hip_bfloat16* w2, float* cwT) {
  int idx = blockIdx.x * 256 + threadIdx.x;
  if (idx < 49152) {
    wq[idx] = __float2bfloat16(qkv_w[idx]);
  } else if (idx < 65536) {
    wp[idx - 49152] = __float2bfloat16(proj_w[idx - 49152]);
  } else if (idx < 131072) {
    w1[idx - 65536] = __float2bfloat16(fc1_w[idx - 65536]);
  } else if (idx < 196608) {
    w2[idx - 131072] = __float2bfloat16(fc2_w[idx - 131072]);
  } else if (idx < 196608 + 27*128) {
    int j = idx - 196608;
    int tap = j >> 7, c = j & 127;
    cwT[tap*128 + c] = conv_w[c*27 + tap];   // (C,1,3,3,3) -> (27,C)
  }
}

// ---------------------------------------------------------------------------
// Kernel 1: LN1 + positional/temporal embed, write h in window-token layout bf16
// ---------------------------------------------------------------------------
__global__ __launch_bounds__(256) void ln1_pe_kernel(
    const float* __restrict__ x, const float* __restrict__ g, const float* __restrict__ b,
    const float* __restrict__ pos, const float* __restrict__ te,
    __hip_bfloat16* __restrict__ hb) {
  int wv = threadIdx.x >> 6, lane = threadIdx.x & 63;
  int tk = blockIdx.x * 4 + wv;                 // tk = wid*256 + n
  int wid = tk >> 8, n = tk & 255;
  int t = n >> 6, gd = (n >> 4) & 3, gh = (n >> 2) & 3, gw = n & 3;
  int wd = wid >> 6, wh = (wid >> 3) & 7, ww = wid & 7;
  int d = wd*4 + gd, h = wh*4 + gh, w = ww*4 + gw;
  size_t xoff = ((size_t)((d*32 + h)*32 + w)*4 + t) * CC;
  float v0 = x[xoff + lane], v1 = x[xoff + lane + 64];
  float s = v0 + v1, sq = v0*v0 + v1*v1;
  for (int m = 32; m; m >>= 1) { s += __shfl_xor(s, m); sq += __shfl_xor(sq, m); }
  float mean = s * (1.f/128.f);
  float var  = sq * (1.f/128.f) - mean*mean;
  float rstd = rsqrtf(var + LNEPS);
  int pb = ((gd*4 + gh)*4 + gw) * CC, tb = t * CC;
  float h0 = (v0 - mean)*rstd*g[lane]    + b[lane]    + pos[pb + lane]    + te[tb + lane];
  float h1 = (v1 - mean)*rstd*g[lane+64] + b[lane+64] + pos[pb + lane+64] + te[tb + lane+64];
  hb[(size_t)tk*CC + lane]      = __float2bfloat16(h0);
  hb[(size_t)tk*CC + lane + 64] = __float2bfloat16(h1);
}

// ---------------------------------------------------------------------------
// GEMM template: 128x128 tile, BK=64, 4 waves, compile-time K (KK).
// Epilogues: per-fragment base + r*stride (index math hoisted out of the
// per-element loop).
// MODE 0: qkv split (q scaled, per-head layout, bf16)
// MODE 1: proj + window-merge scatter to spatial, bf16 (feeds conv)
// MODE 2: fc1 + fast GELU, bf16
// MODE 3: fc2 + bias + residual(yb), fp32 -> d_out
// ---------------------------------------------------------------------------
template <int MODE, int KK>
__global__ __launch_bounds__(256) void gemm_kernel(
    const short* __restrict__ Ag, const short* __restrict__ Wg,
    const float* __restrict__ bias,
    void* __restrict__ out0, const float* __restrict__ resid) {
  __shared__ __align__(16) short As[128*72];
  __shared__ __align__(16) short Bs[128*72];
  const int tid = threadIdx.x;
  const int m0 = blockIdx.x * 128;
  const int n0 = blockIdx.y * 128;
  const int lane = tid & 63, wv = tid >> 6;
  const int wr = wv >> 1, wc = wv & 1;
  const int fr = lane & 15, kg = lane >> 4;

  f32x4 acc[4][4];
#pragma unroll
  for (int i = 0; i < 4; ++i)
#pragma unroll
    for (int j = 0; j < 4; ++j) acc[i][j] = (f32x4)0.f;

#pragma unroll
  for (int kc = 0; kc < KK; kc += 64) {
    __syncthreads();
#pragma unroll
    for (int i = 0; i < 4; ++i) {
      int c = tid + i*256;
      int row = c >> 3, col8 = (c & 7) * 8;
      s16x8 va = *(const s16x8*)(Ag + (size_t)(m0 + row)*KK + kc + col8);
      s16x8 vb = *(const s16x8*)(Wg + (size_t)(n0 + row)*KK + kc + col8);
      *(s16x8*)&As[row*72 + col8] = va;
      *(s16x8*)&Bs[row*72 + col8] = vb;
    }
    __syncthreads();
#pragma unroll
    for (int ks = 0; ks < 2; ++ks) {
      s16x8 a[4], b[4];
#pragma unroll
      for (int i = 0; i < 4; ++i)
        a[i] = *(const s16x8*)&As[(wr*64 + i*16 + fr)*72 + ks*32 + kg*8];
#pragma unroll
      for (int j = 0; j < 4; ++j)
        b[j] = *(const s16x8*)&Bs[(wc*64 + j*16 + fr)*72 + ks*32 + kg*8];
#pragma unroll
      for (int i = 0; i < 4; ++i)
#pragma unroll
        for (int j = 0; j < 4; ++j)
          acc[i][j] = __builtin_amdgcn_mfma_f32_16x16x32_bf16(a[i], b[j], acc[i][j], 0, 0, 0);
    }
  }

  // epilogue — all index math hoisted to per-(i,j) fragment; rows of a
  // fragment are consecutive (row_base%4==0) so dst = base + r*stride.
  const int rowoff = (lane >> 4) * 4;
#pragma unroll
  for (int j = 0; j < 4; ++j) {
    const int col = n0 + wc*64 + j*16 + fr;
    const float bj = bias[col];
    // MODE 0 j-hoists
    const int sec = col >> 7, head = (col >> 4) & 7;
    const float scl = (MODE == 0 && sec == 0) ? SCALE : 1.0f;
    const float bjs = bj * scl;
#pragma unroll
    for (int i = 0; i < 4; ++i) {
      const int row_base = m0 + wr*64 + i*16 + rowoff;
      f32x4 v = acc[i][j];
      if constexpr (MODE == 0) {
        short* qs = (short*)out0;
        const int wid = row_base >> 8, nbase = row_base & 255;
        const int base = sec*8388608 + (wid*8 + head)*4096 + nbase*16 + fr;
#pragma unroll
        for (int r = 0; r < 4; ++r)
          qs[base + r*16] = f2b(fmaf(v[r], scl, bjs));
      } else if constexpr (MODE == 1) {
        short* y1o = (short*)out0;
        const int wid = row_base >> 8, nbase = row_base & 255;
        const int t = nbase >> 6, gd = (nbase >> 4) & 3, gh = (nbase >> 2) & 3;
        const int wd = wid >> 6, wh = (wid >> 3) & 7, ww = wid & 7;
        const int dp = wd*4 + gd, hp = wh*4 + gh, wpb = ww*4;
        const int srb = ((dp*32 + hp)*32 + wpb)*4 + t;
        const int base = srb*CC + col;
#pragma unroll
        for (int r = 0; r < 4; ++r)
          y1o[base + r*512] = f2b(v[r] + bj);
      } else if constexpr (MODE == 2) {
        short* gp = (short*)out0;
        const int base = row_base*512 + col;
#pragma unroll
        for (int r = 0; r < 4; ++r)
          gp[base + r*512] = f2b(fast_gelu(v[r] + bj));
      } else {
        float* outp = (float*)out0;
        const int base = row_base*CC + col;
#pragma unroll
        for (int r = 0; r < 4; ++r)
          outp[base + r*CC] = v[r] + bj + resid[base + r*CC];
      }
    }
  }
}

// ---------------------------------------------------------------------------
// Kernel: MFMA window attention (unchanged from R2).
// ---------------------------------------------------------------------------
#define KPAD 20
#define VPAD 264
__global__ __launch_bounds__(256) void attn_mfma_kernel(
    const __hip_bfloat16* __restrict__ qb, const __hip_bfloat16* __restrict__ kb,
    const __hip_bfloat16* __restrict__ vb, __hip_bfloat16* __restrict__ ob) {
  __shared__ __align__(16) short kL[256*KPAD];
  __shared__ __align__(16) short vT[16*VPAD];
  const int bh = blockIdx.x;                // win*8 + head
  const int wid = bh >> 3, head = bh & 7;
  const int tid = threadIdx.x;
  const short* kg = (const short*)kb + (size_t)bh*4096;
  const short* vg = (const short*)vb + (size_t)bh*4096;
  const short* qg = (const short*)qb + (size_t)bh*4096;
  {
    s16x8 a0 = *(const s16x8*)&kg[tid*16];
    s16x8 a1 = *(const s16x8*)&kg[tid*16 + 8];
    *(s16x8*)&kL[tid*KPAD]     = a0;
    *(s16x8*)&kL[tid*KPAD + 8] = a1;
    s16x8 b0 = *(const s16x8*)&vg[tid*16];
    s16x8 b1 = *(const s16x8*)&vg[tid*16 + 8];
#pragma unroll
    for (int d = 0; d < 8; ++d) {
      vT[d*VPAD + tid]     = b0[d];
      vT[(d+8)*VPAD + tid] = b1[d];
    }
  }
  __syncthreads();
  const int wv = tid >> 6, lane = tid & 63;
  const int fr = lane & 15, hi = lane >> 4;
  s16x4 kfrag[16], vfrag[16];
#pragma unroll
  for (int t = 0; t < 16; ++t) {
    kfrag[t] = *(const s16x4*)&kL[(t*16 + fr)*KPAD + hi*4];
    vfrag[t] = *(const s16x4*)&vT[fr*VPAD + t*16 + hi*4];
  }
  short* obs = (short*)ob;
  for (int qt = 0; qt < 4; ++qt) {
    const int q0 = wv*64 + qt*16;
    s16x4 qfrag = *(const s16x4*)&qg[(q0 + fr)*16 + hi*4];
    f32x4 st[16];
#pragma unroll
    for (int kt = 0; kt < 16; ++kt)
      st[kt] = mfma16x16x16_bf16(kfrag[kt], qfrag, (f32x4)0.f);
    float den = 0.f;
    f32x4 oacc = (f32x4)0.f;
#pragma unroll
    for (int kt = 0; kt < 16; ++kt) {
      float e0 = __expf(st[kt][0]), e1 = __expf(st[kt][1]);
      float e2 = __expf(st[kt][2]), e3 = __expf(st[kt][3]);
      den += (e0 + e1) + (e2 + e3);
      s16x4 pa;
      pa[0] = f2b(e0); pa[1] = f2b(e1); pa[2] = f2b(e2); pa[3] = f2b(e3);
      oacc = mfma16x16x16_bf16(vfrag[kt], pa, oacc);
    }
    den += __shfl_xor(den, 16);
    den += __shfl_xor(den, 32);
    float inv = 1.f / den;
    s16x4 ov;
    ov[0] = f2b(oacc[0]*inv); ov[1] = f2b(oacc[1]*inv);
    ov[2] = f2b(oacc[2]*inv); ov[3] = f2b(oacc[3]*inv);
    *(s16x4*)&obs[((size_t)wid*256 + q0 + fr)*CC + head*16 + hi*4] = ov;
  }
}

// ---------------------------------------------------------------------------
// Kernel: FUSED depthwise 3x3x3 conv (bf16 in) + exln + norm2, t-vectorized
// (unchanged from R4).
// ---------------------------------------------------------------------------
__global__ __launch_bounds__(256) void conv_ln_kernel(
    const __hip_bfloat16* __restrict__ y1b, const float* __restrict__ wT,
    const float* __restrict__ cb,
    const float* __restrict__ exg, const float* __restrict__ exb,
    const float* __restrict__ n2g, const float* __restrict__ n2b,
    float* __restrict__ yb, __hip_bfloat16* __restrict__ h2) {
  const int tid = threadIdx.x;
  const int sp = blockIdx.x*8 + (tid >> 5);      // spatial site (d,h,w)
  const int cbase = (tid & 31) * 4;              // channel group
  const int w = sp & 31, h = (sp >> 5) & 31, d = sp >> 10;
  const short* ys = (const short*)y1b;

  f32x4 bias = *(const f32x4*)&cb[cbase];
  f32x4 acc0 = bias, acc1 = bias, acc2 = bias, acc3 = bias;   // one per t

#pragma unroll
  for (int dd = -1; dd <= 1; ++dd) {
    int dn = d + dd; if ((unsigned)dn >= 16u) continue;
#pragma unroll
    for (int dh = -1; dh <= 1; ++dh) {
      int hn = h + dh; if ((unsigned)hn >= 32u) continue;
#pragma unroll
      for (int dw = -1; dw <= 1; ++dw) {
        int wn = w + dw; if ((unsigned)wn >= 32u) continue;
        int tap = ((dd+1)*3 + (dh+1))*3 + (dw+1);
        f32x4 wv = *(const f32x4*)&wT[tap*CC + cbase];
        const short* base = &ys[(size_t)(((dn*32 + hn)*32 + wn)*4)*CC + cbase];
        s16x4 v0 = *(const s16x4*)(base);
        s16x4 v1 = *(const s16x4*)(base + CC);
        s16x4 v2 = *(const s16x4*)(base + 2*CC);
        s16x4 v3 = *(const s16x4*)(base + 3*CC);
        acc0.x = fmaf(b2f(v0[0]), wv.x, acc0.x); acc0.y = fmaf(b2f(v0[1]), wv.y, acc0.y);
        acc0.z = fmaf(b2f(v0[2]), wv.z, acc0.z); acc0.w = fmaf(b2f(v0[3]), wv.w, acc0.w);
        acc1.x = fmaf(b2f(v1[0]), wv.x, acc1.x); acc1.y = fmaf(b2f(v1[1]), wv.y, acc1.y);
        acc1.z = fmaf(b2f(v1[2]), wv.z, acc1.z); acc1.w = fmaf(b2f(v1[3]), wv.w, acc1.w);
        acc2.x = fmaf(b2f(v2[0]), wv.x, acc2.x); acc2.y = fmaf(b2f(v2[1]), wv.y, acc2.y);
        acc2.z = fmaf(b2f(v2[2]), wv.z, acc2.z); acc2.w = fmaf(b2f(v2[3]), wv.w, acc2.w);
        acc3.x = fmaf(b2f(v3[0]), wv.x, acc3.x); acc3.y = fmaf(b2f(v3[1]), wv.y, acc3.y);
        acc3.z = fmaf(b2f(v3[2]), wv.z, acc3.z); acc3.w = fmaf(b2f(v3[3]), wv.w, acc3.w);
      }
    }
  }

  f32x4 eg = *(const f32x4*)&exg[cbase];
  f32x4 eb = *(const f32x4*)&exb[cbase];
  f32x4 ng = *(const f32x4*)&n2g[cbase];
  f32x4 nb = *(const f32x4*)&n2b[cbase];

  f32x4 accs[4] = {acc0, acc1, acc2, acc3};
#pragma unroll
  for (int t = 0; t < 4; ++t) {
    f32x4 a = accs[t];
    float s  = (a.x + a.y) + (a.z + a.w);
    float sq = (a.x*a.x + a.y*a.y) + (a.z*a.z + a.w*a.w);
#pragma unroll
    for (int m = 1; m <= 16; m <<= 1) { s += __shfl_xor(s, m); sq += __shfl_xor(sq, m); }
    float mean = s * (1.f/128.f);
    float var  = sq * (1.f/128.f) - mean*mean;
    float rstd = rsqrtf(var + LNEPS);
    f32x4 y;
    y.x = (a.x - mean)*rstd*eg.x + eb.x;
    y.y = (a.y - mean)*rstd*eg.y + eb.y;
    y.z = (a.z - mean)*rstd*eg.z + eb.z;
    y.w = (a.w - mean)*rstd*eg.w + eb.w;
    *(f32x4*)&yb[(size_t)(sp*4 + t)*CC + cbase] = y;
    float s2  = (y.x + y.y) + (y.z + y.w);
    float sq2 = (y.x*y.x + y.y*y.y) + (y.z*y.z + y.w*y.w);
#pragma unroll
    for (int m = 1; m <= 16; m <<= 1) { s2 += __shfl_xor(s2, m); sq2 += __shfl_xor(sq2, m); }
    float mean2 = s2 * (1.f/128.f);
    float var2  = sq2 * (1.f/128.f) - mean2*mean2;
    float rstd2 = rsqrtf(var2 + LNEPS);
    s16x4 hb;
    hb[0] = f2b((y.x - mean2)*rstd2*ng.x + nb.x);
    hb[1] = f2b((y.y - mean2)*rstd2*ng.y + nb.y);
    hb[2] = f2b((y.z - mean2)*rstd2*ng.z + nb.z);
    hb[3] = f2b((y.w - mean2)*rstd2*ng.w + nb.w);
    *(s16x4*)&((short*)h2)[(size_t)(sp*4 + t)*CC + cbase] = hb;
  }
}

// ---------------------------------------------------------------------------
// Launch
// ---------------------------------------------------------------------------
extern "C" void kernel_launch(void* const* d_in, const int* in_sizes, int n_in,
                              void* d_out, int out_size, void* d_ws, size_t ws_size,
                              hipStream_t stream) {
  const float* x      = (const float*)d_in[0];
  const float* n1g    = (const float*)d_in[1];
  const float* n1b    = (const float*)d_in[2];
  const float* pos    = (const float*)d_in[3];
  const float* te     = (const float*)d_in[4];
  const float* qkv_w  = (const float*)d_in[5];
  const float* qkv_b  = (const float*)d_in[6];
  const float* proj_w = (const float*)d_in[7];
  const float* proj_b = (const float*)d_in[8];
  const float* conv_w = (const float*)d_in[9];
  const float* conv_b = (const float*)d_in[10];
  const float* exg    = (const float*)d_in[11];
  const float* exb    = (const float*)d_in[12];
  const float* n2g    = (const float*)d_in[13];
  const float* n2b    = (const float*)d_in[14];
  const float* fc1_w  = (const float*)d_in[15];
  const float* fc1_b  = (const float*)d_in[16];
  const float* fc2_w  = (const float*)d_in[17];
  const float* fc2_b  = (const float*)d_in[18];

  char* wsb = (char*)d_ws;
  __hip_bfloat16* wq  = (__hip_bfloat16*)(wsb);             // 384x128
  __hip_bfloat16* wp  = (__hip_bfloat16*)(wsb + 98304);     // 128x128
  __hip_bfloat16* w1  = (__hip_bfloat16*)(wsb + 131072);    // 512x128
  __hip_bfloat16* w2  = (__hip_bfloat16*)(wsb + 262144);    // 128x512
  float*          cwT = (float*)(wsb + 393216);             // 27x128

  const size_t A_OFF = (size_t)1 << 20;                     // 16 MiB region
  const size_t B_OFF = A_OFF + ((size_t)16 << 20);          // 48 MiB region
  const size_t C_OFF = B_OFF + ((size_t)48 << 20);          // 64 MiB region

  __hip_bfloat16* hbuf = (__hip_bfloat16*)(wsb + A_OFF);    // LN1 out
  __hip_bfloat16* obuf = (__hip_bfloat16*)(wsb + A_OFF);    // attn out (reuses A)
  __hip_bfloat16* h2in = (__hip_bfloat16*)(wsb + A_OFF);    // MLP in (reuses A)
  __hip_bfloat16* qkvb = (__hip_bfloat16*)(wsb + B_OFF);    // q|k|v, 16MiB each
  __hip_bfloat16* qb   = qkvb;
  __hip_bfloat16* kb   = qkvb + 8388608;
  __hip_bfloat16* vb   = qkvb + 16777216;
  __hip_bfloat16* y1   = (__hip_bfloat16*)(wsb + B_OFF);    // proj out bf16 (over q)
  float* yb   = (float*)(wsb + B_OFF + ((size_t)16 << 20)); // exln y fp32 (over k,v)
  __hip_bfloat16* gbuf = (__hip_bfloat16*)(wsb + C_OFF);    // GELU out (64 MiB)

  prep_kernel<<<782, 256, 0, stream>>>(qkv_w, proj_w, fc1_w, fc2_w, conv_w,
                                       wq, wp, w1, w2, cwT);
  ln1_pe_kernel<<<TOKS/4, 256, 0, stream>>>(x, n1g, n1b, pos, te, hbuf);
  gemm_kernel<0, 128><<<dim3(TOKS/128, 3), 256, 0, stream>>>(
      (const short*)hbuf, (const short*)wq, qkv_b, (void*)qkvb, nullptr);
  attn_mfma_kernel<<<NWIN*8, 256, 0, stream>>>(qb, kb, vb, obuf);
  gemm_kernel<1, 128><<<dim3(TOKS/128, 1), 256, 0, stream>>>(
      (const short*)obuf, (const short*)wp, proj_b, (void*)y1, nullptr);
  conv_ln_kernel<<<16384/8, 256, 0, stream>>>(y1, cwT, conv_b,
      exg, exb, n2g, n2b, yb, h2in);
  gemm_kernel<2, 128><<<dim3(TOKS/128, 4), 256, 0, stream>>>(
      (const short*)h2in, (const short*)w1, fc1_b, (void*)gbuf, nullptr);
  gemm_kernel<3, 512><<<dim3(TOKS/128, 1), 256, 0, stream>>>(
      (const short*)gbuf, (const short*)w2, fc2_b, (void*)d_out, yb);
}

// Round 7
// 179.305 us; speedup vs baseline: 1.0696x; 1.0696x over previous
//
#include <hip/hip_runtime.h>
#include <hip/hip_bf16.h>

// ---------------------------------------------------------------------------
// CrossFormerBlock on MI355X (gfx950)
// B=1 D=16 H=32 W=32 T=4 C=128, G=4, NH=8, HD=16, NW=256 windows, N=256 tok/win
// R7: GEMM epilogue store fix — swap MFMA operands (acc holds D^T) so each
// lane owns 4 CONSECUTIVE output columns -> vectorized s16x4/f32x4 stores
// (16 vector stores/thread vs 64 scalar 2B stores). Rest unchanged.
// ---------------------------------------------------------------------------

typedef __attribute__((ext_vector_type(8))) short  s16x8;
typedef __attribute__((ext_vector_type(4))) short  s16x4;
typedef __attribute__((ext_vector_type(4))) float  f32x4;

#define CC    128
#define NWIN  256
#define NTOK  256
#define TOKS  65536            // total tokens = NWIN*NTOK = D*H*W*T
#define SCALE 0.25f
#define LNEPS 1e-5f

__device__ __forceinline__ float b2f(short s) {
  union { unsigned u; float f; } c; c.u = ((unsigned)(unsigned short)s) << 16; return c.f;
}
__device__ __forceinline__ short f2b(float f) {
  __hip_bfloat16 h = __float2bfloat16(f);
  return *reinterpret_cast<short*>(&h);
}
__device__ __forceinline__ float fast_gelu(float x) {
  // 0.5x(1+tanh(0.79788456(x+0.044715x^3))) == x * sigmoid(1.59577(x+0.044715x^3))
  float u = 1.595769122f * x * fmaf(0.044715f, x*x, 1.0f);
  return x / (1.0f + __expf(-u));
}

__device__ __forceinline__ f32x4 mfma16x16x16_bf16(s16x4 a, s16x4 b, f32x4 c) {
#if __has_builtin(__builtin_amdgcn_mfma_f32_16x16x16_bf16)
  return __builtin_amdgcn_mfma_f32_16x16x16_bf16(a, b, c, 0, 0, 0);
#elif __has_builtin(__builtin_amdgcn_mfma_f32_16x16x16bf16_1k)
  return __builtin_amdgcn_mfma_f32_16x16x16bf16_1k(a, b, c, 0, 0, 0);
#else
  f32x4 d;
  asm("v_mfma_f32_16x16x16_bf16 %0, %1, %2, %3" : "=v"(d) : "v"(a), "v"(b), "v"(c));
  return d;
#endif
}

// ---------------------------------------------------------------------------
// Kernel 0: weight prep — fp32->bf16 copies of GEMM weights + conv_w transpose
// ---------------------------------------------------------------------------
__global__ void prep_kernel(const float* __restrict__ qkv_w, const float* __restrict__ proj_w,
                            const float* __restrict__ fc1_w, const float* __restrict__ fc2_w,
                            const float* __restrict__ conv_w,
                            __hip_bfloat16* wq, __hip_bfloat16* wp,
                            __hip_bfloat16* w1, __hip_bfloat16* w2, float* cwT) {
  int idx = blockIdx.x * 256 + threadIdx.x;
  if (idx < 49152) {
    wq[idx] = __float2bfloat16(qkv_w[idx]);
  } else if (idx < 65536) {
    wp[idx - 49152] = __float2bfloat16(proj_w[idx - 49152]);
  } else if (idx < 131072) {
    w1[idx - 65536] = __float2bfloat16(fc1_w[idx - 65536]);
  } else if (idx < 196608) {
    w2[idx - 131072] = __float2bfloat16(fc2_w[idx - 131072]);
  } else if (idx < 196608 + 27*128) {
    int j = idx - 196608;
    int tap = j >> 7, c = j & 127;
    cwT[tap*128 + c] = conv_w[c*27 + tap];   // (C,1,3,3,3) -> (27,C)
  }
}

// ---------------------------------------------------------------------------
// Kernel 1: LN1 + positional/temporal embed, write h in window-token layout bf16
// ---------------------------------------------------------------------------
__global__ __launch_bounds__(256) void ln1_pe_kernel(
    const float* __restrict__ x, const float* __restrict__ g, const float* __restrict__ b,
    const float* __restrict__ pos, const float* __restrict__ te,
    __hip_bfloat16* __restrict__ hb) {
  int wv = threadIdx.x >> 6, lane = threadIdx.x & 63;
  int tk = blockIdx.x * 4 + wv;                 // tk = wid*256 + n
  int wid = tk >> 8, n = tk & 255;
  int t = n >> 6, gd = (n >> 4) & 3, gh = (n >> 2) & 3, gw = n & 3;
  int wd = wid >> 6, wh = (wid >> 3) & 7, ww = wid & 7;
  int d = wd*4 + gd, h = wh*4 + gh, w = ww*4 + gw;
  size_t xoff = ((size_t)((d*32 + h)*32 + w)*4 + t) * CC;
  float v0 = x[xoff + lane], v1 = x[xoff + lane + 64];
  float s = v0 + v1, sq = v0*v0 + v1*v1;
  for (int m = 32; m; m >>= 1) { s += __shfl_xor(s, m); sq += __shfl_xor(sq, m); }
  float mean = s * (1.f/128.f);
  float var  = sq * (1.f/128.f) - mean*mean;
  float rstd = rsqrtf(var + LNEPS);
  int pb = ((gd*4 + gh)*4 + gw) * CC, tb = t * CC;
  float h0 = (v0 - mean)*rstd*g[lane]    + b[lane]    + pos[pb + lane]    + te[tb + lane];
  float h1 = (v1 - mean)*rstd*g[lane+64] + b[lane+64] + pos[pb + lane+64] + te[tb + lane+64];
  hb[(size_t)tk*CC + lane]      = __float2bfloat16(h0);
  hb[(size_t)tk*CC + lane + 64] = __float2bfloat16(h1);
}

// ---------------------------------------------------------------------------
// GEMM template: 128x128 tile, BK=64, 4 waves, compile-time K (KK).
// acc[i][j] = mfma(b[j], a[i], acc) -> D^T fragments: lane (fr,kg) holds
// output row m = mbase+fr, cols n = nbase+kg*4+{0..3}  => vector stores.
// MODE 0: qkv split (q scaled, per-head layout, bf16)
// MODE 1: proj + window-merge scatter to spatial, bf16 (feeds conv)
// MODE 2: fc1 + fast GELU, bf16
// MODE 3: fc2 + bias + residual(yb), fp32 -> d_out
// ---------------------------------------------------------------------------
template <int MODE, int KK>
__global__ __launch_bounds__(256) void gemm_kernel(
    const short* __restrict__ Ag, const short* __restrict__ Wg,
    const float* __restrict__ bias,
    void* __restrict__ out0, const float* __restrict__ resid) {
  __shared__ __align__(16) short As[128*72];
  __shared__ __align__(16) short Bs[128*72];
  const int tid = threadIdx.x;
  const int m0 = blockIdx.x * 128;
  const int n0 = blockIdx.y * 128;
  const int lane = tid & 63, wv = tid >> 6;
  const int wr = wv >> 1, wc = wv & 1;
  const int fr = lane & 15, kg = lane >> 4;

  f32x4 acc[4][4];
#pragma unroll
  for (int i = 0; i < 4; ++i)
#pragma unroll
    for (int j = 0; j < 4; ++j) acc[i][j] = (f32x4)0.f;

#pragma unroll
  for (int kc = 0; kc < KK; kc += 64) {
    __syncthreads();
#pragma unroll
    for (int i = 0; i < 4; ++i) {
      int c = tid + i*256;
      int row = c >> 3, col8 = (c & 7) * 8;
      s16x8 va = *(const s16x8*)(Ag + (size_t)(m0 + row)*KK + kc + col8);
      s16x8 vb = *(const s16x8*)(Wg + (size_t)(n0 + row)*KK + kc + col8);
      *(s16x8*)&As[row*72 + col8] = va;
      *(s16x8*)&Bs[row*72 + col8] = vb;
    }
    __syncthreads();
#pragma unroll
    for (int ks = 0; ks < 2; ++ks) {
      s16x8 a[4], b[4];
#pragma unroll
      for (int i = 0; i < 4; ++i)
        a[i] = *(const s16x8*)&As[(wr*64 + i*16 + fr)*72 + ks*32 + kg*8];
#pragma unroll
      for (int j = 0; j < 4; ++j)
        b[j] = *(const s16x8*)&Bs[(wc*64 + j*16 + fr)*72 + ks*32 + kg*8];
#pragma unroll
      for (int i = 0; i < 4; ++i)
#pragma unroll
        for (int j = 0; j < 4; ++j)
          acc[i][j] = __builtin_amdgcn_mfma_f32_16x16x32_bf16(b[j], a[i], acc[i][j], 0, 0, 0);
    }
  }

  // ---- epilogue: lane (fr,kg) of fragment (i,j) owns row m = m0+wr*64+i*16+fr,
  // cols nbb+j*16 .. +3 where nbb = n0+wc*64+kg*4. One 8B/16B store per frag.
  const int nbb = n0 + wc*64 + kg*4;
  f32x4 bj4[4];
#pragma unroll
  for (int j = 0; j < 4; ++j) bj4[j] = *(const f32x4*)&bias[nbb + j*16];

#pragma unroll
  for (int i = 0; i < 4; ++i) {
    const int m = m0 + wr*64 + i*16 + fr;
    if constexpr (MODE == 0) {
      short* qs = (short*)out0;
      const int sec = n0 >> 7;                      // tile width == section width
      const float scl = (sec == 0) ? SCALE : 1.0f;
      const int wid = m >> 8, ntok = m & 255;
      const int rowbase = sec*8388608 + (wid*8)*4096 + ntok*16 + (nbb & 15);
#pragma unroll
      for (int j = 0; j < 4; ++j) {
        const int head = ((nbb + j*16) >> 4) & 7;
        f32x4 v = acc[i][j];
        s16x4 o;
        o[0] = f2b(fmaf(v[0], scl, bj4[j].x*scl));
        o[1] = f2b(fmaf(v[1], scl, bj4[j].y*scl));
        o[2] = f2b(fmaf(v[2], scl, bj4[j].z*scl));
        o[3] = f2b(fmaf(v[3], scl, bj4[j].w*scl));
        *(s16x4*)&qs[rowbase + head*4096] = o;
      }
    } else if constexpr (MODE == 1) {
      short* y1o = (short*)out0;
      const int wid = m >> 8, ntok = m & 255;
      const int t = ntok >> 6, gd = (ntok >> 4) & 3, gh = (ntok >> 2) & 3, gw = ntok & 3;
      const int wd = wid >> 6, wh = (wid >> 3) & 7, ww = wid & 7;
      const int sr = (((wd*4 + gd)*32 + wh*4 + gh)*32 + ww*4 + gw)*4 + t;
      const int base = sr*CC + nbb;
#pragma unroll
      for (int j = 0; j < 4; ++j) {
        f32x4 v = acc[i][j];
        s16x4 o;
        o[0] = f2b(v[0] + bj4[j].x); o[1] = f2b(v[1] + bj4[j].y);
        o[2] = f2b(v[2] + bj4[j].z); o[3] = f2b(v[3] + bj4[j].w);
        *(s16x4*)&y1o[base + j*16] = o;
      }
    } else if constexpr (MODE == 2) {
      short* gp = (short*)out0;
      const int base = m*512 + nbb;
#pragma unroll
      for (int j = 0; j < 4; ++j) {
        f32x4 v = acc[i][j];
        s16x4 o;
        o[0] = f2b(fast_gelu(v[0] + bj4[j].x)); o[1] = f2b(fast_gelu(v[1] + bj4[j].y));
        o[2] = f2b(fast_gelu(v[2] + bj4[j].z)); o[3] = f2b(fast_gelu(v[3] + bj4[j].w));
        *(s16x4*)&gp[base + j*16] = o;
      }
    } else {
      float* outp = (float*)out0;
      const int base = m*CC + nbb;
#pragma unroll
      for (int j = 0; j < 4; ++j) {
        f32x4 v = acc[i][j];
        f32x4 rz = *(const f32x4*)&resid[base + j*16];
        f32x4 o;
        o.x = v[0] + bj4[j].x + rz.x; o.y = v[1] + bj4[j].y + rz.y;
        o.z = v[2] + bj4[j].z + rz.z; o.w = v[3] + bj4[j].w + rz.w;
        *(f32x4*)&outp[base + j*16] = o;
      }
    }
  }
}

// ---------------------------------------------------------------------------
// Kernel: MFMA window attention (unchanged from R2).
// ---------------------------------------------------------------------------
#define KPAD 20
#define VPAD 264
__global__ __launch_bounds__(256) void attn_mfma_kernel(
    const __hip_bfloat16* __restrict__ qb, const __hip_bfloat16* __restrict__ kb,
    const __hip_bfloat16* __restrict__ vb, __hip_bfloat16* __restrict__ ob) {
  __shared__ __align__(16) short kL[256*KPAD];
  __shared__ __align__(16) short vT[16*VPAD];
  const int bh = blockIdx.x;                // win*8 + head
  const int wid = bh >> 3, head = bh & 7;
  const int tid = threadIdx.x;
  const short* kg = (const short*)kb + (size_t)bh*4096;
  const short* vg = (const short*)vb + (size_t)bh*4096;
  const short* qg = (const short*)qb + (size_t)bh*4096;
  {
    s16x8 a0 = *(const s16x8*)&kg[tid*16];
    s16x8 a1 = *(const s16x8*)&kg[tid*16 + 8];
    *(s16x8*)&kL[tid*KPAD]     = a0;
    *(s16x8*)&kL[tid*KPAD + 8] = a1;
    s16x8 b0 = *(const s16x8*)&vg[tid*16];
    s16x8 b1 = *(const s16x8*)&vg[tid*16 + 8];
#pragma unroll
    for (int d = 0; d < 8; ++d) {
      vT[d*VPAD + tid]     = b0[d];
      vT[(d+8)*VPAD + tid] = b1[d];
    }
  }
  __syncthreads();
  const int wv = tid >> 6, lane = tid & 63;
  const int fr = lane & 15, hi = lane >> 4;
  s16x4 kfrag[16], vfrag[16];
#pragma unroll
  for (int t = 0; t < 16; ++t) {
    kfrag[t] = *(const s16x4*)&kL[(t*16 + fr)*KPAD + hi*4];
    vfrag[t] = *(const s16x4*)&vT[fr*VPAD + t*16 + hi*4];
  }
  short* obs = (short*)ob;
  for (int qt = 0; qt < 4; ++qt) {
    const int q0 = wv*64 + qt*16;
    s16x4 qfrag = *(const s16x4*)&qg[(q0 + fr)*16 + hi*4];
    f32x4 st[16];
#pragma unroll
    for (int kt = 0; kt < 16; ++kt)
      st[kt] = mfma16x16x16_bf16(kfrag[kt], qfrag, (f32x4)0.f);
    float den = 0.f;
    f32x4 oacc = (f32x4)0.f;
#pragma unroll
    for (int kt = 0; kt < 16; ++kt) {
      float e0 = __expf(st[kt][0]), e1 = __expf(st[kt][1]);
      float e2 = __expf(st[kt][2]), e3 = __expf(st[kt][3]);
      den += (e0 + e1) + (e2 + e3);
      s16x4 pa;
      pa[0] = f2b(e0); pa[1] = f2b(e1); pa[2] = f2b(e2); pa[3] = f2b(e3);
      oacc = mfma16x16x16_bf16(vfrag[kt], pa, oacc);
    }
    den += __shfl_xor(den, 16);
    den += __shfl_xor(den, 32);
    float inv = 1.f / den;
    s16x4 ov;
    ov[0] = f2b(oacc[0]*inv); ov[1] = f2b(oacc[1]*inv);
    ov[2] = f2b(oacc[2]*inv); ov[3] = f2b(oacc[3]*inv);
    *(s16x4*)&obs[((size_t)wid*256 + q0 + fr)*CC + head*16 + hi*4] = ov;
  }
}

// ---------------------------------------------------------------------------
// Kernel: FUSED depthwise 3x3x3 conv (bf16 in) + exln + norm2, t-vectorized
// (unchanged from R4).
// ---------------------------------------------------------------------------
__global__ __launch_bounds__(256) void conv_ln_kernel(
    const __hip_bfloat16* __restrict__ y1b, const float* __restrict__ wT,
    const float* __restrict__ cb,
    const float* __restrict__ exg, const float* __restrict__ exb,
    const float* __restrict__ n2g, const float* __restrict__ n2b,
    float* __restrict__ yb, __hip_bfloat16* __restrict__ h2) {
  const int tid = threadIdx.x;
  const int sp = blockIdx.x*8 + (tid >> 5);      // spatial site (d,h,w)
  const int cbase = (tid & 31) * 4;              // channel group
  const int w = sp & 31, h = (sp >> 5) & 31, d = sp >> 10;
  const short* ys = (const short*)y1b;

  f32x4 bias = *(const f32x4*)&cb[cbase];
  f32x4 acc0 = bias, acc1 = bias, acc2 = bias, acc3 = bias;   // one per t

#pragma unroll
  for (int dd = -1; dd <= 1; ++dd) {
    int dn = d + dd; if ((unsigned)dn >= 16u) continue;
#pragma unroll
    for (int dh = -1; dh <= 1; ++dh) {
      int hn = h + dh; if ((unsigned)hn >= 32u) continue;
#pragma unroll
      for (int dw = -1; dw <= 1; ++dw) {
        int wn = w + dw; if ((unsigned)wn >= 32u) continue;
        int tap = ((dd+1)*3 + (dh+1))*3 + (dw+1);
        f32x4 wv = *(const f32x4*)&wT[tap*CC + cbase];
        const short* base = &ys[(size_t)(((dn*32 + hn)*32 + wn)*4)*CC + cbase];
        s16x4 v0 = *(const s16x4*)(base);
        s16x4 v1 = *(const s16x4*)(base + CC);
        s16x4 v2 = *(const s16x4*)(base + 2*CC);
        s16x4 v3 = *(const s16x4*)(base + 3*CC);
        acc0.x = fmaf(b2f(v0[0]), wv.x, acc0.x); acc0.y = fmaf(b2f(v0[1]), wv.y, acc0.y);
        acc0.z = fmaf(b2f(v0[2]), wv.z, acc0.z); acc0.w = fmaf(b2f(v0[3]), wv.w, acc0.w);
        acc1.x = fmaf(b2f(v1[0]), wv.x, acc1.x); acc1.y = fmaf(b2f(v1[1]), wv.y, acc1.y);
        acc1.z = fmaf(b2f(v1[2]), wv.z, acc1.z); acc1.w = fmaf(b2f(v1[3]), wv.w, acc1.w);
        acc2.x = fmaf(b2f(v2[0]), wv.x, acc2.x); acc2.y = fmaf(b2f(v2[1]), wv.y, acc2.y);
        acc2.z = fmaf(b2f(v2[2]), wv.z, acc2.z); acc2.w = fmaf(b2f(v2[3]), wv.w, acc2.w);
        acc3.x = fmaf(b2f(v3[0]), wv.x, acc3.x); acc3.y = fmaf(b2f(v3[1]), wv.y, acc3.y);
        acc3.z = fmaf(b2f(v3[2]), wv.z, acc3.z); acc3.w = fmaf(b2f(v3[3]), wv.w, acc3.w);
      }
    }
  }

  f32x4 eg = *(const f32x4*)&exg[cbase];
  f32x4 eb = *(const f32x4*)&exb[cbase];
  f32x4 ng = *(const f32x4*)&n2g[cbase];
  f32x4 nb = *(const f32x4*)&n2b[cbase];

  f32x4 accs[4] = {acc0, acc1, acc2, acc3};
#pragma unroll
  for (int t = 0; t < 4; ++t) {
    f32x4 a = accs[t];
    float s  = (a.x + a.y) + (a.z + a.w);
    float sq = (a.x*a.x + a.y*a.y) + (a.z*a.z + a.w*a.w);
#pragma unroll
    for (int m = 1; m <= 16; m <<= 1) { s += __shfl_xor(s, m); sq += __shfl_xor(sq, m); }
    float mean = s * (1.f/128.f);
    float var  = sq * (1.f/128.f) - mean*mean;
    float rstd = rsqrtf(var + LNEPS);
    f32x4 y;
    y.x = (a.x - mean)*rstd*eg.x + eb.x;
    y.y = (a.y - mean)*rstd*eg.y + eb.y;
    y.z = (a.z - mean)*rstd*eg.z + eb.z;
    y.w = (a.w - mean)*rstd*eg.w + eb.w;
    *(f32x4*)&yb[(size_t)(sp*4 + t)*CC + cbase] = y;
    float s2  = (y.x + y.y) + (y.z + y.w);
    float sq2 = (y.x*y.x + y.y*y.y) + (y.z*y.z + y.w*y.w);
#pragma unroll
    for (int m = 1; m <= 16; m <<= 1) { s2 += __shfl_xor(s2, m); sq2 += __shfl_xor(sq2, m); }
    float mean2 = s2 * (1.f/128.f);
    float var2  = sq2 * (1.f/128.f) - mean2*mean2;
    float rstd2 = rsqrtf(var2 + LNEPS);
    s16x4 hb;
    hb[0] = f2b((y.x - mean2)*rstd2*ng.x + nb.x);
    hb[1] = f2b((y.y - mean2)*rstd2*ng.y + nb.y);
    hb[2] = f2b((y.z - mean2)*rstd2*ng.z + nb.z);
    hb[3] = f2b((y.w - mean2)*rstd2*ng.w + nb.w);
    *(s16x4*)&((short*)h2)[(size_t)(sp*4 + t)*CC + cbase] = hb;
  }
}

// ---------------------------------------------------------------------------
// Launch
// ---------------------------------------------------------------------------
extern "C" void kernel_launch(void* const* d_in, const int* in_sizes, int n_in,
                              void* d_out, int out_size, void* d_ws, size_t ws_size,
                              hipStream_t stream) {
  const float* x      = (const float*)d_in[0];
  const float* n1g    = (const float*)d_in[1];
  const float* n1b    = (const float*)d_in[2];
  const float* pos    = (const float*)d_in[3];
  const float* te     = (const float*)d_in[4];
  const float* qkv_w  = (const float*)d_in[5];
  const float* qkv_b  = (const float*)d_in[6];
  const float* proj_w = (const float*)d_in[7];
  const float* proj_b = (const float*)d_in[8];
  const float* conv_w = (const float*)d_in[9];
  const float* conv_b = (const float*)d_in[10];
  const float* exg    = (const float*)d_in[11];
  const float* exb    = (const float*)d_in[12];
  const float* n2g    = (const float*)d_in[13];
  const float* n2b    = (const float*)d_in[14];
  const float* fc1_w  = (const float*)d_in[15];
  const float* fc1_b  = (const float*)d_in[16];
  const float* fc2_w  = (const float*)d_in[17];
  const float* fc2_b  = (const float*)d_in[18];

  char* wsb = (char*)d_ws;
  __hip_bfloat16* wq  = (__hip_bfloat16*)(wsb);             // 384x128
  __hip_bfloat16* wp  = (__hip_bfloat16*)(wsb + 98304);     // 128x128
  __hip_bfloat16* w1  = (__hip_bfloat16*)(wsb + 131072);    // 512x128
  __hip_bfloat16* w2  = (__hip_bfloat16*)(wsb + 262144);    // 128x512
  float*          cwT = (float*)(wsb + 393216);             // 27x128

  const size_t A_OFF = (size_t)1 << 20;                     // 16 MiB region
  const size_t B_OFF = A_OFF + ((size_t)16 << 20);          // 48 MiB region
  const size_t C_OFF = B_OFF + ((size_t)48 << 20);          // 64 MiB region

  __hip_bfloat16* hbuf = (__hip_bfloat16*)(wsb + A_OFF);    // LN1 out
  __hip_bfloat16* obuf = (__hip_bfloat16*)(wsb + A_OFF);    // attn out (reuses A)
  __hip_bfloat16* h2in = (__hip_bfloat16*)(wsb + A_OFF);    // MLP in (reuses A)
  __hip_bfloat16* qkvb = (__hip_bfloat16*)(wsb + B_OFF);    // q|k|v, 16MiB each
  __hip_bfloat16* qb   = qkvb;
  __hip_bfloat16* kb   = qkvb + 8388608;
  __hip_bfloat16* vb   = qkvb + 16777216;
  __hip_bfloat16* y1   = (__hip_bfloat16*)(wsb + B_OFF);    // proj out bf16 (over q)
  float* yb   = (float*)(wsb + B_OFF + ((size_t)16 << 20)); // exln y fp32 (over k,v)
  __hip_bfloat16* gbuf = (__hip_bfloat16*)(wsb + C_OFF);    // GELU out (64 MiB)

  prep_kernel<<<782, 256, 0, stream>>>(qkv_w, proj_w, fc1_w, fc2_w, conv_w,
                                       wq, wp, w1, w2, cwT);
  ln1_pe_kernel<<<TOKS/4, 256, 0, stream>>>(x, n1g, n1b, pos, te, hbuf);
  gemm_kernel<0, 128><<<dim3(TOKS/128, 3), 256, 0, stream>>>(
      (const short*)hbuf, (const short*)wq, qkv_b, (void*)qkvb, nullptr);
  attn_mfma_kernel<<<NWIN*8, 256, 0, stream>>>(qb, kb, vb, obuf);
  gemm_kernel<1, 128><<<dim3(TOKS/128, 1), 256, 0, stream>>>(
      (const short*)obuf, (const short*)wp, proj_b, (void*)y1, nullptr);
  conv_ln_kernel<<<16384/8, 256, 0, stream>>>(y1, cwT, conv_b,
      exg, exb, n2g, n2b, yb, h2in);
  gemm_kernel<2, 128><<<dim3(TOKS/128, 4), 256, 0, stream>>>(
      (const short*)h2in, (const short*)w1, fc1_b, (void*)gbuf, nullptr);
  gemm_kernel<3, 512><<<dim3(TOKS/128, 1), 256, 0, stream>>>(
      (const short*)gbuf, (const short*)w2, fc2_b, (void*)d_out, yb);
}